// Round 16
// baseline (226.486 us; speedup 1.0000x reference)
//
#include <hip/hip_runtime.h>
#include <hip/hip_bf16.h>

#define B_    64
#define HID_  4096
#define HQ_   32
#define HKV_  8
#define D_    128
#define BS_   16
#define MAXB_ 64

#define KS      16                // K-split both GEMMs (kchunk 256)
#define KCHUNK  (HID_ / KS)       // 256
#define QKV_ROWS 6144
#define O_ROWS   4096
#define SPLITS  16                // flash-decode token splits

#define REGION_SZ ((size_t)KS * QKV_ROWS * 64)
#define QKVF_SZ  ((size_t)64 * 6144)
#define XB_SZ    ((size_t)HID_ * 64)

typedef __attribute__((ext_vector_type(8))) short bf16x8;
typedef __attribute__((ext_vector_type(4))) float f32x4;

__device__ inline unsigned short f2bf(float x) {
  __hip_bfloat16 h = __float2bfloat16(x);
  union { __hip_bfloat16 b; unsigned short u; } v; v.b = h;
  return v.u;
}
__device__ inline float bf2f(unsigned short h) {
  union { float f; unsigned u; } v; v.u = ((unsigned)h) << 16;
  return v.f;
}

// ---------------------------------------------------------------------------
// Convert X [64][HID] fp32 -> fragment-contiguous bf16 hi/lo.
// ---------------------------------------------------------------------------
__global__ __launch_bounds__(256) void convert_x(
    const float* __restrict__ X, unsigned short* __restrict__ XBhi,
    unsigned short* __restrict__ XBlo)
{
  int idx = blockIdx.x * 256 + threadIdx.x;
  int kg = idx >> 6, b = idx & 63;
  const float* xp = X + (size_t)b * HID_ + kg * 8;
  float4 a = *(const float4*)xp, c = *(const float4*)(xp + 4);
  float xs[8] = {a.x, a.y, a.z, a.w, c.x, c.y, c.z, c.w};
  unsigned short hi[8], lo[8];
  #pragma unroll
  for (int j = 0; j < 8; ++j) {
    hi[j] = f2bf(xs[j]);
    lo[j] = f2bf(xs[j] - bf2f(hi[j]));
  }
  *(uint4*)(XBhi + (size_t)idx * 8) = *(const uint4*)hi;
  *(uint4*)(XBlo + (size_t)idx * 8) = *(const uint4*)lo;
}

// ---------------------------------------------------------------------------
// Split-bf16 MFMA skinny GEMM partial (r13 geometry).
// Wave = 32 rows (2 row-tiles) x 64 batches (4 col-tiles of 16x16x32).
// A (W) fp32 direct from global, cvt in-register; B from XB (L2).
// 3 MFMA: hi*hi + lo*hi + hi*lo. part[ks][row][64batch].
// ---------------------------------------------------------------------------
__global__ __launch_bounds__(256, 4) void gemm_mfma(
    const float* __restrict__ W0, const float* __restrict__ W1,
    const float* __restrict__ W2,
    const unsigned short* __restrict__ XBhi,
    const unsigned short* __restrict__ XBlo,
    int split1, int split2, int rows_total, float* __restrict__ part)
{
  const int tid = threadIdx.x;
  const int l   = tid & 63;
  const int w   = tid >> 6;
  const int r0  = blockIdx.x * 128 + w * 32;
  const int k0  = blockIdx.y * KCHUNK;

  const float* W; int rloc;
  if (r0 < split1)      { W = W0; rloc = r0; }
  else if (r0 < split2) { W = W1; rloc = r0 - split1; }
  else                  { W = W2; rloc = r0 - split2; }

  const int lm = l & 15;
  const int lk = l >> 4;

  const float* wp0 = W + (size_t)(rloc + lm) * HID_ + k0 + lk * 8;
  const float* wp1 = wp0 + (size_t)16 * HID_;
  const unsigned short* bh = XBhi + ((size_t)(k0 / 8 + lk) * 64 + lm) * 8;
  const unsigned short* bl = XBlo + ((size_t)(k0 / 8 + lk) * 64 + lm) * 8;

  f32x4 acc[2][4];
  #pragma unroll
  for (int rt = 0; rt < 2; ++rt)
    #pragma unroll
    for (int ct = 0; ct < 4; ++ct)
      #pragma unroll
      for (int i = 0; i < 4; ++i) acc[rt][ct][i] = 0.f;

  #pragma unroll 4
  for (int ks = 0; ks < KCHUNK / 32; ++ks) {
    bf16x8 Bh[4], Bl[4];
    #pragma unroll
    for (int ct = 0; ct < 4; ++ct) {
      Bh[ct] = *(const bf16x8*)(bh + (size_t)ks * 2048 + ct * 128);
      Bl[ct] = *(const bf16x8*)(bl + (size_t)ks * 2048 + ct * 128);
    }
    #pragma unroll
    for (int rt = 0; rt < 2; ++rt) {
      const float* wp = (rt ? wp1 : wp0) + ks * 32;
      float4 a0 = *(const float4*)wp;
      float4 a1 = *(const float4*)(wp + 4);
      float xs[8] = {a0.x, a0.y, a0.z, a0.w, a1.x, a1.y, a1.z, a1.w};
      bf16x8 Ah, Al;
      #pragma unroll
      for (int j = 0; j < 8; ++j) {
        unsigned short h = f2bf(xs[j]);
        Ah[j] = (short)h;
        Al[j] = (short)f2bf(xs[j] - bf2f(h));
      }
      #pragma unroll
      for (int ct = 0; ct < 4; ++ct) {
        acc[rt][ct] = __builtin_amdgcn_mfma_f32_16x16x32_bf16(Ah, Bh[ct], acc[rt][ct], 0, 0, 0);
        acc[rt][ct] = __builtin_amdgcn_mfma_f32_16x16x32_bf16(Al, Bh[ct], acc[rt][ct], 0, 0, 0);
        acc[rt][ct] = __builtin_amdgcn_mfma_f32_16x16x32_bf16(Ah, Bl[ct], acc[rt][ct], 0, 0, 0);
      }
    }
  }

  #pragma unroll
  for (int rt = 0; rt < 2; ++rt)
    #pragma unroll
    for (int ct = 0; ct < 4; ++ct) {
      int row = r0 + rt * 16 + lk * 4;
      int bat = ct * 16 + lm;
      #pragma unroll
      for (int i = 0; i < 4; ++i)
        part[((size_t)blockIdx.y * rows_total + row + i) * 64 + bat] = acc[rt][ct][i];
    }
}

// ---------------------------------------------------------------------------
// Sum K-split partials + RoPE (half-split). q scaled by 1/sqrt(D).
// qkvf layout: q[64][32][128] | k[64][8][128] | v[64][8][128]
// ---------------------------------------------------------------------------
__global__ __launch_bounds__(256) void reduce_rope(
    const float* __restrict__ part, const float* __restrict__ cosT,
    const float* __restrict__ sinT, const int* __restrict__ positions,
    float* __restrict__ qkvf)
{
  const int bb  = threadIdx.x & 63;
  const int cid = blockIdx.x * 4 + (threadIdx.x >> 6);
  const int pos = positions[bb];

  if (cid < 2048) {
    const int hq = cid >> 6, d0 = cid & 63;
    const int r1 = hq * 128 + d0;
    float x1 = 0.f, x2 = 0.f;
    #pragma unroll 8
    for (int ks = 0; ks < KS; ++ks) {
      x1 += part[((size_t)ks * QKV_ROWS + r1) * 64 + bb];
      x2 += part[((size_t)ks * QKV_ROWS + r1 + 64) * 64 + bb];
    }
    float c = cosT[pos * 64 + d0], s = sinT[pos * 64 + d0];
    const float scale = 0.08838834764831843f;
    qkvf[(size_t)(bb * 32 + hq) * 128 + d0]      = (x1 * c - x2 * s) * scale;
    qkvf[(size_t)(bb * 32 + hq) * 128 + d0 + 64] = (x2 * c + x1 * s) * scale;
  } else if (cid < 2560) {
    const int c2 = cid - 2048;
    const int kh = c2 >> 6, d0 = c2 & 63;
    const int r1 = 4096 + kh * 128 + d0;
    float x1 = 0.f, x2 = 0.f;
    #pragma unroll 8
    for (int ks = 0; ks < KS; ++ks) {
      x1 += part[((size_t)ks * QKV_ROWS + r1) * 64 + bb];
      x2 += part[((size_t)ks * QKV_ROWS + r1 + 64) * 64 + bb];
    }
    float c = cosT[pos * 64 + d0], s = sinT[pos * 64 + d0];
    qkvf[262144 + (size_t)(bb * 8 + kh) * 128 + d0]      = x1 * c - x2 * s;
    qkvf[262144 + (size_t)(bb * 8 + kh) * 128 + d0 + 64] = x2 * c + x1 * s;
  } else {
    const int c2 = cid - 2560;
    const int kh = c2 >> 6, d0 = c2 & 63;
    const int r1 = 5120 + kh * 128 + d0;
    float x1 = 0.f, x2 = 0.f;
    #pragma unroll 8
    for (int ks = 0; ks < KS; ++ks) {
      x1 += part[((size_t)ks * QKV_ROWS + r1) * 64 + bb];
      x2 += part[((size_t)ks * QKV_ROWS + r1 + 64) * 64 + bb];
    }
    qkvf[327680 + (size_t)(bb * 8 + kh) * 128 + d0]      = x1;
    qkvf[327680 + (size_t)(bb * 8 + kh) * 128 + d0 + 64] = x2;
  }
}

// ---------------------------------------------------------------------------
// Single-pass online-softmax flash-decode split (SPLITS=16).
// ---------------------------------------------------------------------------
__global__ __launch_bounds__(256, 4) void attn_split(
    const float* __restrict__ qkvf, const float* __restrict__ kcache,
    const float* __restrict__ vcache, const int* __restrict__ btab,
    const int* __restrict__ ctxlen,
    float* __restrict__ part_o,   // [B*HKV*SPLITS][4][128]
    float* __restrict__ part_ml)  // [B*HKV*SPLITS][4][2]
{
  const int bid = blockIdx.x;
  const int s   = bid & (SPLITS - 1);
  const int bh  = bid >> 4;
  const int b = bh >> 3, h = bh & 7;
  const int ctx   = ctxlen[b];
  const int chunk = (ctx + SPLITS - 1) / SPLITS;   // <= 64
  const int t0 = s * chunk;
  const int t1 = min(ctx, t0 + chunk);
  const int last = ctx - 1;
  const int tEnd = min(t1, last);

  const int tid  = threadIdx.x;
  const int half = tid >> 5;
  const int d4   = tid & 31;

  __shared__ int   sblk[8];
  __shared__ float wm[4][4], wl[4][4];
  __shared__ float wacc[4][4][128];

  const int blk0 = t0 >> 4;
  if (tid < 8) {
    int ib = blk0 + tid;
    sblk[tid] = (ib < MAXB_) ? btab[b * MAXB_ + ib] : 0;
  }
  __syncthreads();

  float4 qf[4];
  #pragma unroll
  for (int g = 0; g < 4; ++g)
    qf[g] = *(const float4*)(qkvf + (size_t)(b * 32 + h * 4 + g) * 128 + d4 * 4);

  float m[4], l[4], acc[4][4];
  #pragma unroll
  for (int g = 0; g < 4; ++g) {
    m[g] = -1e30f; l[g] = 0.f;
    #pragma unroll
    for (int j = 0; j < 4; ++j) acc[g][j] = 0.f;
  }

  for (int t = t0 + half; t < tEnd; t += 8) {
    int slot = sblk[(t >> 4) - blk0] * BS_ + (t & 15);
    const float* base = kcache + ((size_t)slot * HKV_ + h) * D_ + d4 * 4;
    const float* vbas = vcache + ((size_t)slot * HKV_ + h) * D_ + d4 * 4;
    float4 kv = *(const float4*)base;
    float4 vv = *(const float4*)vbas;

    float p0 = qf[0].x * kv.x + qf[0].y * kv.y + qf[0].z * kv.z + qf[0].w * kv.w;
    float p1 = qf[1].x * kv.x + qf[1].y * kv.y + qf[1].z * kv.z + qf[1].w * kv.w;
    float p2 = qf[2].x * kv.x + qf[2].y * kv.y + qf[2].z * kv.z + qf[2].w * kv.w;
    float p3 = qf[3].x * kv.x + qf[3].y * kv.y + qf[3].z * kv.z + qf[3].w * kv.w;
    #pragma unroll
    for (int mm = 16; mm >= 1; mm >>= 1) {
      p0 += __shfl_xor(p0, mm);
      p1 += __shfl_xor(p1, mm);
      p2 += __shfl_xor(p2, mm);
      p3 += __shfl_xor(p3, mm);
    }
    float pg[4] = {p0, p1, p2, p3};
    #pragma unroll
    for (int g = 0; g < 4; ++g) {
      float nm = fmaxf(m[g], pg[g]);
      float sc = __expf(m[g] - nm);
      float pe = __expf(pg[g] - nm);
      l[g] = l[g] * sc + pe;
      acc[g][0] = acc[g][0] * sc + pe * vv.x;
      acc[g][1] = acc[g][1] * sc + pe * vv.y;
      acc[g][2] = acc[g][2] * sc + pe * vv.z;
      acc[g][3] = acc[g][3] * sc + pe * vv.w;
      m[g] = nm;
    }
  }

  if (t1 > last && half == ((last - t0) & 7)) {
    const float* kp = qkvf + 262144 + (size_t)(b * 8 + h) * 128 + d4 * 4;
    const float* vp = qkvf + 327680 + (size_t)(b * 8 + h) * 128 + d4 * 4;
    float4 kv = *(const float4*)kp;
    float4 vv = *(const float4*)vp;
    float p0 = qf[0].x * kv.x + qf[0].y * kv.y + qf[0].z * kv.z + qf[0].w * kv.w;
    float p1 = qf[1].x * kv.x + qf[1].y * kv.y + qf[1].z * kv.z + qf[1].w * kv.w;
    float p2 = qf[2].x * kv.x + qf[2].y * kv.y + qf[2].z * kv.z + qf[2].w * kv.w;
    float p3 = qf[3].x * kv.x + qf[3].y * kv.y + qf[3].z * kv.z + qf[3].w * kv.w;
    #pragma unroll
    for (int mm = 16; mm >= 1; mm >>= 1) {
      p0 += __shfl_xor(p0, mm);
      p1 += __shfl_xor(p1, mm);
      p2 += __shfl_xor(p2, mm);
      p3 += __shfl_xor(p3, mm);
    }
    float pg[4] = {p0, p1, p2, p3};
    #pragma unroll
    for (int g = 0; g < 4; ++g) {
      float nm = fmaxf(m[g], pg[g]);
      float sc = __expf(m[g] - nm);
      float pe = __expf(pg[g] - nm);
      l[g] = l[g] * sc + pe;
      acc[g][0] = acc[g][0] * sc + pe * vv.x;
      acc[g][1] = acc[g][1] * sc + pe * vv.y;
      acc[g][2] = acc[g][2] * sc + pe * vv.z;
      acc[g][3] = acc[g][3] * sc + pe * vv.w;
      m[g] = nm;
    }
  }

  #pragma unroll
  for (int g = 0; g < 4; ++g) {
    float om = __shfl_xor(m[g], 32);
    float ol = __shfl_xor(l[g], 32);
    float M  = fmaxf(m[g], om);
    float s0 = __expf(m[g] - M);
    float s1 = __expf(om - M);
    l[g] = l[g] * s0 + ol * s1;
    #pragma unroll
    for (int j = 0; j < 4; ++j) {
      float oa = __shfl_xor(acc[g][j], 32);
      acc[g][j] = acc[g][j] * s0 + oa * s1;
    }
    m[g] = M;
  }
  if ((tid & 32) == 0) {
    int wv = tid >> 6;
    if (d4 == 0) {
      #pragma unroll
      for (int g = 0; g < 4; ++g) { wm[wv][g] = m[g]; wl[wv][g] = l[g]; }
    }
    #pragma unroll
    for (int g = 0; g < 4; ++g)
      #pragma unroll
      for (int j = 0; j < 4; ++j)
        wacc[wv][g][d4 * 4 + j] = acc[g][j];
  }
  __syncthreads();

  for (int idx = tid; idx < 512; idx += 256) {
    int g = idx >> 7, d = idx & 127;
    float M4 = fmaxf(fmaxf(wm[0][g], wm[1][g]), fmaxf(wm[2][g], wm[3][g]));
    float e0 = __expf(wm[0][g] - M4), e1 = __expf(wm[1][g] - M4);
    float e2 = __expf(wm[2][g] - M4), e3 = __expf(wm[3][g] - M4);
    float num = wacc[0][g][d] * e0 + wacc[1][g][d] * e1
              + wacc[2][g][d] * e2 + wacc[3][g][d] * e3;
    part_o[(size_t)bid * 512 + idx] = num;
    if (d == 0) {
      float lt = wl[0][g] * e0 + wl[1][g] * e1 + wl[2][g] * e2 + wl[3][g] * e3;
      part_ml[(size_t)bid * 8 + g * 2]     = M4;
      part_ml[(size_t)bid * 8 + g * 2 + 1] = lt;
    }
  }
}

// ---------------------------------------------------------------------------
// Combine SPLITS=16 partials AND emit bf16 hi/lo XB layout for the O-GEMM.
// ---------------------------------------------------------------------------
__global__ __launch_bounds__(256) void attn_combine_xb(
    const float* __restrict__ part_o, const float* __restrict__ part_ml,
    unsigned short* __restrict__ XBhi, unsigned short* __restrict__ XBlo)
{
  const int bh = blockIdx.x;
  const int b = bh >> 3, h = bh & 7;
  const int tid = threadIdx.x;

  __shared__ float Sg[SPLITS][4];
  __shared__ float Dg[4];

  if (tid < 64) {                        // lane = s*4+g, s=0..15
    int s = tid >> 2, g = tid & 3;
    float m = part_ml[((size_t)bh * SPLITS + s) * 8 + g * 2];
    float l = part_ml[((size_t)bh * SPLITS + s) * 8 + g * 2 + 1];
    float M = m;
    #pragma unroll
    for (int k = 4; k <= 32; k <<= 1) M = fmaxf(M, __shfl_xor(M, k));
    float scl = __expf(m - M);
    float dl = l * scl;
    #pragma unroll
    for (int k = 4; k <= 32; k <<= 1) dl += __shfl_xor(dl, k);
    Sg[s][g] = scl;
    if (s == 0) Dg[g] = dl;
  }
  __syncthreads();

  for (int idx = tid; idx < 512; idx += 256) {
    int g = idx >> 7, d = idx & 127;
    float num = 0.f;
    #pragma unroll
    for (int s = 0; s < SPLITS; ++s)
      num += Sg[s][g] * part_o[((size_t)bh * SPLITS + s) * 512 + idx];
    float val = num / Dg[g];
    int col = (h * 4 + g) * 128 + d;
    int kg = col >> 3, j = col & 7;
    unsigned short hi = f2bf(val);
    unsigned short lo = f2bf(val - bf2f(hi));
    XBhi[((size_t)kg * 64 + b) * 8 + j] = hi;
    XBlo[((size_t)kg * 64 + b) * 8 + j] = lo;
  }
}

// ---------------------------------------------------------------------------
// Sum KS partials of O-GEMM ([ks][row][batch]) -> out[b][row] via LDS
// transpose, coalesced both sides.
// ---------------------------------------------------------------------------
__global__ __launch_bounds__(256) void reduce_out_t(
    const float* __restrict__ part, float* __restrict__ out)
{
  __shared__ float t[64][65];
  const int i0 = blockIdx.x * 64;
  const int lane = threadIdx.x & 63, q = threadIdx.x >> 6;

  #pragma unroll
  for (int rr = q; rr < 64; rr += 4) {
    float s = 0.f;
    #pragma unroll 8
    for (int ks = 0; ks < KS; ++ks)
      s += part[((size_t)ks * O_ROWS + i0 + rr) * 64 + lane];
    t[rr][lane] = s;
  }
  __syncthreads();
  #pragma unroll
  for (int rr = q; rr < 64; rr += 4)
    out[(size_t)rr * O_ROWS + i0 + lane] = t[lane][rr];
}

// ---------------------------------------------------------------------------
// ATTRIBUTION ROUND: both gemm_mfma launches are issued TWICE (idempotent —
// pure function of unchanged inputs, writes identical values). The dur_us
// delta vs round 15 (185.2 us) isolates t(gemm_QKV)+t(gemm_O)+launch ovh.
// ---------------------------------------------------------------------------
extern "C" void kernel_launch(void* const* d_in, const int* in_sizes, int n_in,
                              void* d_out, int out_size, void* d_ws, size_t ws_size,
                              hipStream_t stream)
{
  (void)in_sizes; (void)n_in; (void)out_size; (void)ws_size;
  const float* hidden    = (const float*)d_in[0];
  const int*   positions = (const int*)d_in[1];
  const float* cosT      = (const float*)d_in[2];
  const float* sinT      = (const float*)d_in[3];
  const float* kcache    = (const float*)d_in[4];
  const float* vcache    = (const float*)d_in[5];
  const int*   btab      = (const int*)d_in[7];
  const int*   ctx       = (const int*)d_in[8];
  const float* Wq        = (const float*)d_in[9];
  const float* Wk        = (const float*)d_in[10];
  const float* Wv        = (const float*)d_in[11];
  const float* Wo        = (const float*)d_in[12];
  float* out = (float*)d_out;

  float* ws      = (float*)d_ws;
  float* region  = ws;                       // reused 3x
  float* qkvf    = region + REGION_SZ;
  unsigned short* XBhi = (unsigned short*)(qkvf + QKVF_SZ);
  unsigned short* XBlo = XBhi + XB_SZ;
  float* part1   = region;                                     // phase 1
  float* part_o  = region;                                     // phase 2
  float* part_ml = region + (size_t)B_ * HKV_ * SPLITS * 512;
  float* part3   = region;                                     // phase 3

  convert_x<<<128, 256, 0, stream>>>(hidden, XBhi, XBlo);
  gemm_mfma<<<dim3(QKV_ROWS / 128, KS), 256, 0, stream>>>(
      Wq, Wk, Wv, XBhi, XBlo, 4096, 5120, QKV_ROWS, part1);
  gemm_mfma<<<dim3(QKV_ROWS / 128, KS), 256, 0, stream>>>(   // duplicate (diag)
      Wq, Wk, Wv, XBhi, XBlo, 4096, 5120, QKV_ROWS, part1);
  reduce_rope<<<768, 256, 0, stream>>>(part1, cosT, sinT, positions, qkvf);
  attn_split<<<B_ * HKV_ * SPLITS, 256, 0, stream>>>(
      qkvf, kcache, vcache, btab, ctx, part_o, part_ml);
  attn_combine_xb<<<B_ * HKV_, 256, 0, stream>>>(part_o, part_ml, XBhi, XBlo);
  gemm_mfma<<<dim3(O_ROWS / 128, KS), 256, 0, stream>>>(
      Wo, Wo, Wo, XBhi, XBlo, O_ROWS, O_ROWS, O_ROWS, part3);
  gemm_mfma<<<dim3(O_ROWS / 128, KS), 256, 0, stream>>>(     // duplicate (diag)
      Wo, Wo, Wo, XBhi, XBlo, O_ROWS, O_ROWS, O_ROWS, part3);
  reduce_out_t<<<O_ROWS / 64, 256, 0, stream>>>(part3, out);
}

// Round 17
// 192.377 us; speedup vs baseline: 1.1773x; 1.1773x over previous
//
#include <hip/hip_runtime.h>
#include <hip/hip_bf16.h>

#define B_    64
#define HID_  4096
#define HQ_   32
#define HKV_  8
#define D_    128
#define BS_   16
#define MAXB_ 64

#define KS      16                // K-split both GEMMs (kchunk 256)
#define KCHUNK  (HID_ / KS)       // 256
#define QKV_ROWS 6144
#define O_ROWS   4096
#define SPLITS  16                // flash-decode token splits

#define REGION_SZ ((size_t)KS * QKV_ROWS * 64)
#define QKVF_SZ  ((size_t)64 * 6144)
#define XB_SZ    ((size_t)HID_ * 64)

typedef __attribute__((ext_vector_type(8))) short bf16x8;
typedef __attribute__((ext_vector_type(4))) float f32x4;

__device__ inline unsigned short f2bf(float x) {
  __hip_bfloat16 h = __float2bfloat16(x);
  union { __hip_bfloat16 b; unsigned short u; } v; v.b = h;
  return v.u;
}
__device__ inline float bf2f(unsigned short h) {
  union { float f; unsigned u; } v; v.u = ((unsigned)h) << 16;
  return v.f;
}

// ---------------------------------------------------------------------------
// Convert X [64][HID] fp32 -> fragment-contiguous bf16 hi/lo.
// ---------------------------------------------------------------------------
__global__ __launch_bounds__(256) void convert_x(
    const float* __restrict__ X, unsigned short* __restrict__ XBhi,
    unsigned short* __restrict__ XBlo)
{
  int idx = blockIdx.x * 256 + threadIdx.x;
  int kg = idx >> 6, b = idx & 63;
  const float* xp = X + (size_t)b * HID_ + kg * 8;
  float4 a = *(const float4*)xp, c = *(const float4*)(xp + 4);
  float xs[8] = {a.x, a.y, a.z, a.w, c.x, c.y, c.z, c.w};
  unsigned short hi[8], lo[8];
  #pragma unroll
  for (int j = 0; j < 8; ++j) {
    hi[j] = f2bf(xs[j]);
    lo[j] = f2bf(xs[j] - bf2f(hi[j]));
  }
  *(uint4*)(XBhi + (size_t)idx * 8) = *(const uint4*)hi;
  *(uint4*)(XBlo + (size_t)idx * 8) = *(const uint4*)lo;
}

// ---------------------------------------------------------------------------
// Split-bf16 MFMA skinny GEMM partial (r13 geometry).
// Wave = 32 rows (2 row-tiles) x 64 batches (4 col-tiles of 16x16x32).
// A (W) fp32 direct from global, cvt in-register; B from XB (L2).
// 3 MFMA: hi*hi + lo*hi + hi*lo. part[ks][row][64batch].
// ---------------------------------------------------------------------------
__global__ __launch_bounds__(256, 4) void gemm_mfma(
    const float* __restrict__ W0, const float* __restrict__ W1,
    const float* __restrict__ W2,
    const unsigned short* __restrict__ XBhi,
    const unsigned short* __restrict__ XBlo,
    int split1, int split2, int rows_total, float* __restrict__ part)
{
  const int tid = threadIdx.x;
  const int l   = tid & 63;
  const int w   = tid >> 6;
  const int r0  = blockIdx.x * 128 + w * 32;
  const int k0  = blockIdx.y * KCHUNK;

  const float* W; int rloc;
  if (r0 < split1)      { W = W0; rloc = r0; }
  else if (r0 < split2) { W = W1; rloc = r0 - split1; }
  else                  { W = W2; rloc = r0 - split2; }

  const int lm = l & 15;
  const int lk = l >> 4;

  const float* wp0 = W + (size_t)(rloc + lm) * HID_ + k0 + lk * 8;
  const float* wp1 = wp0 + (size_t)16 * HID_;
  const unsigned short* bh = XBhi + ((size_t)(k0 / 8 + lk) * 64 + lm) * 8;
  const unsigned short* bl = XBlo + ((size_t)(k0 / 8 + lk) * 64 + lm) * 8;

  f32x4 acc[2][4];
  #pragma unroll
  for (int rt = 0; rt < 2; ++rt)
    #pragma unroll
    for (int ct = 0; ct < 4; ++ct)
      #pragma unroll
      for (int i = 0; i < 4; ++i) acc[rt][ct][i] = 0.f;

  #pragma unroll 4
  for (int ks = 0; ks < KCHUNK / 32; ++ks) {
    bf16x8 Bh[4], Bl[4];
    #pragma unroll
    for (int ct = 0; ct < 4; ++ct) {
      Bh[ct] = *(const bf16x8*)(bh + (size_t)ks * 2048 + ct * 128);
      Bl[ct] = *(const bf16x8*)(bl + (size_t)ks * 2048 + ct * 128);
    }
    #pragma unroll
    for (int rt = 0; rt < 2; ++rt) {
      const float* wp = (rt ? wp1 : wp0) + ks * 32;
      float4 a0 = *(const float4*)wp;
      float4 a1 = *(const float4*)(wp + 4);
      float xs[8] = {a0.x, a0.y, a0.z, a0.w, a1.x, a1.y, a1.z, a1.w};
      bf16x8 Ah, Al;
      #pragma unroll
      for (int j = 0; j < 8; ++j) {
        unsigned short h = f2bf(xs[j]);
        Ah[j] = (short)h;
        Al[j] = (short)f2bf(xs[j] - bf2f(h));
      }
      #pragma unroll
      for (int ct = 0; ct < 4; ++ct) {
        acc[rt][ct] = __builtin_amdgcn_mfma_f32_16x16x32_bf16(Ah, Bh[ct], acc[rt][ct], 0, 0, 0);
        acc[rt][ct] = __builtin_amdgcn_mfma_f32_16x16x32_bf16(Al, Bh[ct], acc[rt][ct], 0, 0, 0);
        acc[rt][ct] = __builtin_amdgcn_mfma_f32_16x16x32_bf16(Ah, Bl[ct], acc[rt][ct], 0, 0, 0);
      }
    }
  }

  #pragma unroll
  for (int rt = 0; rt < 2; ++rt)
    #pragma unroll
    for (int ct = 0; ct < 4; ++ct) {
      int row = r0 + rt * 16 + lk * 4;
      int bat = ct * 16 + lm;
      #pragma unroll
      for (int i = 0; i < 4; ++i)
        part[((size_t)blockIdx.y * rows_total + row + i) * 64 + bat] = acc[rt][ct][i];
    }
}

// ---------------------------------------------------------------------------
// Sum K-split partials + RoPE (half-split). q scaled by 1/sqrt(D).
// qkvf layout: q[64][32][128] | k[64][8][128] | v[64][8][128]
// ---------------------------------------------------------------------------
__global__ __launch_bounds__(256) void reduce_rope(
    const float* __restrict__ part, const float* __restrict__ cosT,
    const float* __restrict__ sinT, const int* __restrict__ positions,
    float* __restrict__ qkvf)
{
  const int bb  = threadIdx.x & 63;
  const int cid = blockIdx.x * 4 + (threadIdx.x >> 6);
  const int pos = positions[bb];

  if (cid < 2048) {
    const int hq = cid >> 6, d0 = cid & 63;
    const int r1 = hq * 128 + d0;
    float x1 = 0.f, x2 = 0.f;
    #pragma unroll 8
    for (int ks = 0; ks < KS; ++ks) {
      x1 += part[((size_t)ks * QKV_ROWS + r1) * 64 + bb];
      x2 += part[((size_t)ks * QKV_ROWS + r1 + 64) * 64 + bb];
    }
    float c = cosT[pos * 64 + d0], s = sinT[pos * 64 + d0];
    const float scale = 0.08838834764831843f;
    qkvf[(size_t)(bb * 32 + hq) * 128 + d0]      = (x1 * c - x2 * s) * scale;
    qkvf[(size_t)(bb * 32 + hq) * 128 + d0 + 64] = (x2 * c + x1 * s) * scale;
  } else if (cid < 2560) {
    const int c2 = cid - 2048;
    const int kh = c2 >> 6, d0 = c2 & 63;
    const int r1 = 4096 + kh * 128 + d0;
    float x1 = 0.f, x2 = 0.f;
    #pragma unroll 8
    for (int ks = 0; ks < KS; ++ks) {
      x1 += part[((size_t)ks * QKV_ROWS + r1) * 64 + bb];
      x2 += part[((size_t)ks * QKV_ROWS + r1 + 64) * 64 + bb];
    }
    float c = cosT[pos * 64 + d0], s = sinT[pos * 64 + d0];
    qkvf[262144 + (size_t)(bb * 8 + kh) * 128 + d0]      = x1 * c - x2 * s;
    qkvf[262144 + (size_t)(bb * 8 + kh) * 128 + d0 + 64] = x2 * c + x1 * s;
  } else {
    const int c2 = cid - 2560;
    const int kh = c2 >> 6, d0 = c2 & 63;
    const int r1 = 5120 + kh * 128 + d0;
    float x1 = 0.f, x2 = 0.f;
    #pragma unroll 8
    for (int ks = 0; ks < KS; ++ks) {
      x1 += part[((size_t)ks * QKV_ROWS + r1) * 64 + bb];
      x2 += part[((size_t)ks * QKV_ROWS + r1 + 64) * 64 + bb];
    }
    qkvf[327680 + (size_t)(bb * 8 + kh) * 128 + d0]      = x1;
    qkvf[327680 + (size_t)(bb * 8 + kh) * 128 + d0 + 64] = x2;
  }
}

// ---------------------------------------------------------------------------
// CONTIGUOUS-STREAM flash-decode split: block = (b, split). 256 threads read
// the FULL 4KB K row [slot][8 heads][128] per token (perfectly coalesced);
// group h = tid>>5 runs the online softmax for kv-head h over ALL chunk
// tokens -> no cross-group merge. Consecutive tokens = contiguous 4KB rows.
// ---------------------------------------------------------------------------
__global__ __launch_bounds__(256, 4) void attn_split(
    const float* __restrict__ qkvf, const float* __restrict__ kcache,
    const float* __restrict__ vcache, const int* __restrict__ btab,
    const int* __restrict__ ctxlen,
    float* __restrict__ part_o,   // [B*HKV][SPLITS][512]
    float* __restrict__ part_ml)  // [B*HKV][SPLITS][8]
{
  const int bid = blockIdx.x;            // b*SPLITS + s
  const int s   = bid & (SPLITS - 1);
  const int b   = bid >> 4;              // SPLITS=16
  const int ctx   = ctxlen[b];
  const int chunk = (ctx + SPLITS - 1) / SPLITS;   // <= 64
  const int t0 = s * chunk;
  const int t1 = min(ctx, t0 + chunk);
  const int last = ctx - 1;
  const int tEnd = min(t1, last);

  const int tid = threadIdx.x;
  const int h   = tid >> 5;              // kv-head 0..7
  const int d4  = tid & 31;

  __shared__ int sblk[8];
  const int blk0 = t0 >> 4;
  if (tid < 8) {
    int ib = blk0 + tid;
    sblk[tid] = (ib < MAXB_) ? btab[b * MAXB_ + ib] : 0;
  }
  __syncthreads();

  float4 qf[4];
  #pragma unroll
  for (int g = 0; g < 4; ++g)
    qf[g] = *(const float4*)(qkvf + (size_t)(b * 32 + h * 4 + g) * 128 + d4 * 4);

  float m[4], l[4], acc[4][4];
  #pragma unroll
  for (int g = 0; g < 4; ++g) {
    m[g] = -1e30f; l[g] = 0.f;
    #pragma unroll
    for (int j = 0; j < 4; ++j) acc[g][j] = 0.f;
  }

  #pragma unroll 2
  for (int t = t0; t < tEnd; ++t) {
    int slot = sblk[(t >> 4) - blk0] * BS_ + (t & 15);
    // 256 threads cover the slot's full [8][128] row: tid*16B contiguous
    const float* kp = kcache + ((size_t)slot * HKV_ + h) * D_ + d4 * 4;
    const float* vp = vcache + ((size_t)slot * HKV_ + h) * D_ + d4 * 4;
    float4 kv = *(const float4*)kp;
    float4 vv = *(const float4*)vp;

    float p0 = qf[0].x * kv.x + qf[0].y * kv.y + qf[0].z * kv.z + qf[0].w * kv.w;
    float p1 = qf[1].x * kv.x + qf[1].y * kv.y + qf[1].z * kv.z + qf[1].w * kv.w;
    float p2 = qf[2].x * kv.x + qf[2].y * kv.y + qf[2].z * kv.z + qf[2].w * kv.w;
    float p3 = qf[3].x * kv.x + qf[3].y * kv.y + qf[3].z * kv.z + qf[3].w * kv.w;
    #pragma unroll
    for (int mm = 16; mm >= 1; mm >>= 1) {   // stays within 32-lane group
      p0 += __shfl_xor(p0, mm);
      p1 += __shfl_xor(p1, mm);
      p2 += __shfl_xor(p2, mm);
      p3 += __shfl_xor(p3, mm);
    }
    float pg[4] = {p0, p1, p2, p3};
    #pragma unroll
    for (int g = 0; g < 4; ++g) {
      float nm = fmaxf(m[g], pg[g]);
      float sc = __expf(m[g] - nm);
      float pe = __expf(pg[g] - nm);
      l[g] = l[g] * sc + pe;
      acc[g][0] = acc[g][0] * sc + pe * vv.x;
      acc[g][1] = acc[g][1] * sc + pe * vv.y;
      acc[g][2] = acc[g][2] * sc + pe * vv.z;
      acc[g][3] = acc[g][3] * sc + pe * vv.w;
      m[g] = nm;
    }
  }

  // fresh roped k/v for the final token (virtual cache scatter); guard t0
  if (t0 <= last && t1 > last) {
    const float* kp = qkvf + 262144 + (size_t)(b * 8 + h) * 128 + d4 * 4;
    const float* vp = qkvf + 327680 + (size_t)(b * 8 + h) * 128 + d4 * 4;
    float4 kv = *(const float4*)kp;
    float4 vv = *(const float4*)vp;
    float p0 = qf[0].x * kv.x + qf[0].y * kv.y + qf[0].z * kv.z + qf[0].w * kv.w;
    float p1 = qf[1].x * kv.x + qf[1].y * kv.y + qf[1].z * kv.z + qf[1].w * kv.w;
    float p2 = qf[2].x * kv.x + qf[2].y * kv.y + qf[2].z * kv.z + qf[2].w * kv.w;
    float p3 = qf[3].x * kv.x + qf[3].y * kv.y + qf[3].z * kv.z + qf[3].w * kv.w;
    #pragma unroll
    for (int mm = 16; mm >= 1; mm >>= 1) {
      p0 += __shfl_xor(p0, mm);
      p1 += __shfl_xor(p1, mm);
      p2 += __shfl_xor(p2, mm);
      p3 += __shfl_xor(p3, mm);
    }
    float pg[4] = {p0, p1, p2, p3};
    #pragma unroll
    for (int g = 0; g < 4; ++g) {
      float nm = fmaxf(m[g], pg[g]);
      float sc = __expf(m[g] - nm);
      float pe = __expf(pg[g] - nm);
      l[g] = l[g] * sc + pe;
      acc[g][0] = acc[g][0] * sc + pe * vv.x;
      acc[g][1] = acc[g][1] * sc + pe * vv.y;
      acc[g][2] = acc[g][2] * sc + pe * vv.z;
      acc[g][3] = acc[g][3] * sc + pe * vv.w;
      m[g] = nm;
    }
  }

  // each group writes its own partial; no cross-group merge needed
  float* po = part_o + ((size_t)(b * 8 + h) * SPLITS + s) * 512;
  #pragma unroll
  for (int g = 0; g < 4; ++g)
    #pragma unroll
    for (int j = 0; j < 4; ++j)
      po[g * 128 + d4 * 4 + j] = acc[g][j];
  if (d4 == 0) {
    float* pm = part_ml + ((size_t)(b * 8 + h) * SPLITS + s) * 8;
    #pragma unroll
    for (int g = 0; g < 4; ++g) { pm[g * 2] = m[g]; pm[g * 2 + 1] = l[g]; }
  }
}

// ---------------------------------------------------------------------------
// Combine SPLITS partials AND emit bf16 hi/lo XB layout for the O-GEMM.
// ---------------------------------------------------------------------------
__global__ __launch_bounds__(256) void attn_combine_xb(
    const float* __restrict__ part_o, const float* __restrict__ part_ml,
    unsigned short* __restrict__ XBhi, unsigned short* __restrict__ XBlo)
{
  const int bh = blockIdx.x;
  const int b = bh >> 3, h = bh & 7;
  const int tid = threadIdx.x;

  __shared__ float ml[SPLITS][8];
  __shared__ float Sg[SPLITS][4];
  __shared__ float Dg[4];

  if (tid < SPLITS * 8)
    ml[tid >> 3][tid & 7] = part_ml[(size_t)bh * SPLITS * 8 + tid];
  __syncthreads();

  if (tid < 4) {                        // g
    float M = -1e30f;
    #pragma unroll
    for (int s = 0; s < SPLITS; ++s) M = fmaxf(M, ml[s][tid * 2]);
    float D = 0.f;
    #pragma unroll
    for (int s = 0; s < SPLITS; ++s) {
      float e = __expf(ml[s][tid * 2] - M);
      Sg[s][tid] = e;
      D += e * ml[s][tid * 2 + 1];
    }
    Dg[tid] = D;
  }
  __syncthreads();

  for (int idx = tid; idx < 512; idx += 256) {
    int g = idx >> 7, d = idx & 127;
    float num = 0.f;
    #pragma unroll
    for (int s = 0; s < SPLITS; ++s)
      num += Sg[s][g] * part_o[((size_t)bh * SPLITS + s) * 512 + idx];
    float val = num / Dg[g];
    int col = (h * 4 + g) * 128 + d;
    int kg = col >> 3, j = col & 7;
    unsigned short hi = f2bf(val);
    unsigned short lo = f2bf(val - bf2f(hi));
    XBhi[((size_t)kg * 64 + b) * 8 + j] = hi;
    XBlo[((size_t)kg * 64 + b) * 8 + j] = lo;
  }
}

// ---------------------------------------------------------------------------
// Sum KS partials of O-GEMM ([ks][row][batch]) -> out[b][row] via LDS
// transpose, coalesced both sides.
// ---------------------------------------------------------------------------
__global__ __launch_bounds__(256) void reduce_out_t(
    const float* __restrict__ part, float* __restrict__ out)
{
  __shared__ float t[64][65];
  const int i0 = blockIdx.x * 64;
  const int lane = threadIdx.x & 63, q = threadIdx.x >> 6;

  #pragma unroll
  for (int rr = q; rr < 64; rr += 4) {
    float s = 0.f;
    #pragma unroll 8
    for (int ks = 0; ks < KS; ++ks)
      s += part[((size_t)ks * O_ROWS + i0 + rr) * 64 + lane];
    t[rr][lane] = s;
  }
  __syncthreads();
  #pragma unroll
  for (int rr = q; rr < 64; rr += 4)
    out[(size_t)rr * O_ROWS + i0 + lane] = t[lane][rr];
}

// ---------------------------------------------------------------------------
extern "C" void kernel_launch(void* const* d_in, const int* in_sizes, int n_in,
                              void* d_out, int out_size, void* d_ws, size_t ws_size,
                              hipStream_t stream)
{
  (void)in_sizes; (void)n_in; (void)out_size; (void)ws_size;
  const float* hidden    = (const float*)d_in[0];
  const int*   positions = (const int*)d_in[1];
  const float* cosT      = (const float*)d_in[2];
  const float* sinT      = (const float*)d_in[3];
  const float* kcache    = (const float*)d_in[4];
  const float* vcache    = (const float*)d_in[5];
  const int*   btab      = (const int*)d_in[7];
  const int*   ctx       = (const int*)d_in[8];
  const float* Wq        = (const float*)d_in[9];
  const float* Wk        = (const float*)d_in[10];
  const float* Wv        = (const float*)d_in[11];
  const float* Wo        = (const float*)d_in[12];
  float* out = (float*)d_out;

  float* ws      = (float*)d_ws;
  float* region  = ws;                       // reused 3x
  float* qkvf    = region + REGION_SZ;
  unsigned short* XBhi = (unsigned short*)(qkvf + QKVF_SZ);
  unsigned short* XBlo = XBhi + XB_SZ;
  float* part1   = region;                                     // phase 1
  float* part_o  = region;                                     // phase 2
  float* part_ml = region + (size_t)B_ * HKV_ * SPLITS * 512;
  float* part3   = region;                                     // phase 3

  convert_x<<<128, 256, 0, stream>>>(hidden, XBhi, XBlo);
  gemm_mfma<<<dim3(QKV_ROWS / 128, KS), 256, 0, stream>>>(
      Wq, Wk, Wv, XBhi, XBlo, 4096, 5120, QKV_ROWS, part1);
  reduce_rope<<<768, 256, 0, stream>>>(part1, cosT, sinT, positions, qkvf);
  attn_split<<<B_ * SPLITS, 256, 0, stream>>>(
      qkvf, kcache, vcache, btab, ctx, part_o, part_ml);
  attn_combine_xb<<<B_ * HKV_, 256, 0, stream>>>(part_o, part_ml, XBhi, XBlo);
  gemm_mfma<<<dim3(O_ROWS / 128, KS), 256, 0, stream>>>(
      Wo, Wo, Wo, XBhi, XBlo, O_ROWS, O_ROWS, O_ROWS, part3);
  reduce_out_t<<<O_ROWS / 64, 256, 0, stream>>>(part3, out);
}

// Round 18
// 183.471 us; speedup vs baseline: 1.2345x; 1.0485x over previous
//
#include <hip/hip_runtime.h>
#include <hip/hip_bf16.h>

#define B_    64
#define HID_  4096
#define HQ_   32
#define HKV_  8
#define D_    128
#define BS_   16
#define MAXB_ 64

#define KS      16                // K-split both GEMMs (chunk 256, 8 steps)
#define KCHUNK  (HID_ / KS)       // 256
#define QKV_ROWS 6144
#define O_ROWS   4096
#define SPLITS  8

#define REGION_SZ ((size_t)KS * QKV_ROWS * 64)    // 6.3M floats (max overlay)
#define QKVF_SZ  ((size_t)64 * 6144)
#define XB_SZ    ((size_t)HID_ * 64)

typedef __attribute__((ext_vector_type(8))) short bf16x8;
typedef __attribute__((ext_vector_type(4))) float f32x4;

// Native bf16 conversion: compiler pairs these into v_cvt_pk_bf16_f32.
__device__ inline unsigned short f2bf(float x) {
  __hip_bfloat16 h = __float2bfloat16(x);           // HW RNE
  union { __hip_bfloat16 b; unsigned short u; } v; v.b = h;
  return v.u;
}
__device__ inline float bf2f(unsigned short h) {
  union { float f; unsigned u; } v; v.u = ((unsigned)h) << 16;  // 1 shift
  return v.f;
}

// ---------------------------------------------------------------------------
// Convert X [64][HID] fp32 -> fragment-contiguous bf16 hi/lo.
// ---------------------------------------------------------------------------
__global__ __launch_bounds__(256) void convert_x(
    const float* __restrict__ X, unsigned short* __restrict__ XBhi,
    unsigned short* __restrict__ XBlo)
{
  int idx = blockIdx.x * 256 + threadIdx.x;   // 0..32767
  int kg = idx >> 6, b = idx & 63;
  const float* xp = X + (size_t)b * HID_ + kg * 8;
  float4 a = *(const float4*)xp, c = *(const float4*)(xp + 4);
  float xs[8] = {a.x, a.y, a.z, a.w, c.x, c.y, c.z, c.w};
  unsigned short hi[8], lo[8];
  #pragma unroll
  for (int j = 0; j < 8; ++j) {
    hi[j] = f2bf(xs[j]);
    lo[j] = f2bf(xs[j] - bf2f(hi[j]));
  }
  *(uint4*)(XBhi + (size_t)idx * 8) = *(const uint4*)hi;
  *(uint4*)(XBlo + (size_t)idx * 8) = *(const uint4*)lo;
}

// ---------------------------------------------------------------------------
// Split-bf16 MFMA skinny GEMM partial (r8 geometry, KS=16, native cvt).
// Wave = 32 rows (2 row-tiles) x 64 batches (4 col-tiles of 16x16x32).
// A (W) fp32 direct from global, cvt in-register (v_cvt_pk_bf16_f32 path);
// B from XB (L2). 3 MFMA: hi*hi + lo*hi + hi*lo. part[ks][row][64batch].
// ---------------------------------------------------------------------------
__global__ __launch_bounds__(256, 4) void gemm_mfma(
    const float* __restrict__ W0, const float* __restrict__ W1,
    const float* __restrict__ W2,
    const unsigned short* __restrict__ XBhi,
    const unsigned short* __restrict__ XBlo,
    int split1, int split2, int rows_total, float* __restrict__ part)
{
  const int tid = threadIdx.x;
  const int l   = tid & 63;
  const int w   = tid >> 6;
  const int r0  = blockIdx.x * 128 + w * 32;
  const int k0  = blockIdx.y * KCHUNK;

  const float* W; int rloc;
  if (r0 < split1)      { W = W0; rloc = r0; }
  else if (r0 < split2) { W = W1; rloc = r0 - split1; }
  else                  { W = W2; rloc = r0 - split2; }

  const int lm = l & 15;
  const int lk = l >> 4;

  const float* wp0 = W + (size_t)(rloc + lm) * HID_ + k0 + lk * 8;
  const float* wp1 = wp0 + (size_t)16 * HID_;
  const unsigned short* bh = XBhi + ((size_t)(k0 / 8 + lk) * 64 + lm) * 8;
  const unsigned short* bl = XBlo + ((size_t)(k0 / 8 + lk) * 64 + lm) * 8;

  f32x4 acc[2][4];
  #pragma unroll
  for (int rt = 0; rt < 2; ++rt)
    #pragma unroll
    for (int ct = 0; ct < 4; ++ct)
      #pragma unroll
      for (int i = 0; i < 4; ++i) acc[rt][ct][i] = 0.f;

  #pragma unroll 2
  for (int ks = 0; ks < KCHUNK / 32; ++ks) {
    bf16x8 Bh[4], Bl[4];
    #pragma unroll
    for (int ct = 0; ct < 4; ++ct) {
      Bh[ct] = *(const bf16x8*)(bh + (size_t)ks * 2048 + ct * 128);
      Bl[ct] = *(const bf16x8*)(bl + (size_t)ks * 2048 + ct * 128);
    }
    #pragma unroll
    for (int rt = 0; rt < 2; ++rt) {
      const float* wp = (rt ? wp1 : wp0) + ks * 32;
      float4 a0 = *(const float4*)wp;
      float4 a1 = *(const float4*)(wp + 4);
      float xs[8] = {a0.x, a0.y, a0.z, a0.w, a1.x, a1.y, a1.z, a1.w};
      bf16x8 Ah, Al;
      #pragma unroll
      for (int j = 0; j < 8; ++j) {
        unsigned short h = f2bf(xs[j]);
        Ah[j] = (short)h;
        Al[j] = (short)f2bf(xs[j] - bf2f(h));
      }
      #pragma unroll
      for (int ct = 0; ct < 4; ++ct) {
        acc[rt][ct] = __builtin_amdgcn_mfma_f32_16x16x32_bf16(Ah, Bh[ct], acc[rt][ct], 0, 0, 0);
        acc[rt][ct] = __builtin_amdgcn_mfma_f32_16x16x32_bf16(Al, Bh[ct], acc[rt][ct], 0, 0, 0);
        acc[rt][ct] = __builtin_amdgcn_mfma_f32_16x16x32_bf16(Ah, Bl[ct], acc[rt][ct], 0, 0, 0);
      }
    }
  }

  #pragma unroll
  for (int rt = 0; rt < 2; ++rt)
    #pragma unroll
    for (int ct = 0; ct < 4; ++ct) {
      int row = r0 + rt * 16 + lk * 4;
      int bat = ct * 16 + lm;
      #pragma unroll
      for (int i = 0; i < 4; ++i)
        part[((size_t)blockIdx.y * rows_total + row + i) * 64 + bat] = acc[rt][ct][i];
    }
}

// ---------------------------------------------------------------------------
// Sum K-split partials + RoPE (half-split). q scaled by 1/sqrt(D).
// qkvf layout: q[64][32][128] | k[64][8][128] | v[64][8][128]
// ---------------------------------------------------------------------------
__global__ __launch_bounds__(256) void reduce_rope(
    const float* __restrict__ part, const float* __restrict__ cosT,
    const float* __restrict__ sinT, const int* __restrict__ positions,
    float* __restrict__ qkvf)
{
  const int bb  = threadIdx.x & 63;
  const int cid = blockIdx.x * 4 + (threadIdx.x >> 6);
  const int pos = positions[bb];

  if (cid < 2048) {
    const int hq = cid >> 6, d0 = cid & 63;
    const int r1 = hq * 128 + d0;
    float x1 = 0.f, x2 = 0.f;
    #pragma unroll 8
    for (int ks = 0; ks < KS; ++ks) {
      x1 += part[((size_t)ks * QKV_ROWS + r1) * 64 + bb];
      x2 += part[((size_t)ks * QKV_ROWS + r1 + 64) * 64 + bb];
    }
    float c = cosT[pos * 64 + d0], s = sinT[pos * 64 + d0];
    const float scale = 0.08838834764831843f;
    qkvf[(size_t)(bb * 32 + hq) * 128 + d0]      = (x1 * c - x2 * s) * scale;
    qkvf[(size_t)(bb * 32 + hq) * 128 + d0 + 64] = (x2 * c + x1 * s) * scale;
  } else if (cid < 2560) {
    const int c2 = cid - 2048;
    const int kh = c2 >> 6, d0 = c2 & 63;
    const int r1 = 4096 + kh * 128 + d0;
    float x1 = 0.f, x2 = 0.f;
    #pragma unroll 8
    for (int ks = 0; ks < KS; ++ks) {
      x1 += part[((size_t)ks * QKV_ROWS + r1) * 64 + bb];
      x2 += part[((size_t)ks * QKV_ROWS + r1 + 64) * 64 + bb];
    }
    float c = cosT[pos * 64 + d0], s = sinT[pos * 64 + d0];
    qkvf[262144 + (size_t)(bb * 8 + kh) * 128 + d0]      = x1 * c - x2 * s;
    qkvf[262144 + (size_t)(bb * 8 + kh) * 128 + d0 + 64] = x2 * c + x1 * s;
  } else {
    const int c2 = cid - 2560;
    const int kh = c2 >> 6, d0 = c2 & 63;
    const int r1 = 5120 + kh * 128 + d0;
    float x1 = 0.f, x2 = 0.f;
    #pragma unroll 8
    for (int ks = 0; ks < KS; ++ks) {
      x1 += part[((size_t)ks * QKV_ROWS + r1) * 64 + bb];
      x2 += part[((size_t)ks * QKV_ROWS + r1 + 64) * 64 + bb];
    }
    qkvf[327680 + (size_t)(bb * 8 + kh) * 128 + d0]      = x1;
    qkvf[327680 + (size_t)(bb * 8 + kh) * 128 + d0 + 64] = x2;
  }
}

// ---------------------------------------------------------------------------
// Single-pass online-softmax flash-decode split (r12 version).
// ---------------------------------------------------------------------------
__global__ __launch_bounds__(256, 4) void attn_split(
    const float* __restrict__ qkvf, const float* __restrict__ kcache,
    const float* __restrict__ vcache, const int* __restrict__ btab,
    const int* __restrict__ ctxlen,
    float* __restrict__ part_o,   // [B*HKV*SPLITS][4][128]
    float* __restrict__ part_ml)  // [B*HKV*SPLITS][4][2]
{
  const int bid = blockIdx.x;
  const int s   = bid & (SPLITS - 1);
  const int bh  = bid >> 3;
  const int b = bh >> 3, h = bh & 7;
  const int ctx   = ctxlen[b];
  const int chunk = (ctx + SPLITS - 1) / SPLITS;
  const int t0 = s * chunk;
  const int t1 = min(ctx, t0 + chunk);
  const int last = ctx - 1;
  const int tEnd = min(t1, last);

  const int tid  = threadIdx.x;
  const int half = tid >> 5;
  const int d4   = tid & 31;

  __shared__ int   sblk[16];
  __shared__ float wm[4][4], wl[4][4];
  __shared__ float wacc[4][4][128];

  const int blk0 = t0 >> 4;
  if (tid < 16) {
    int ib = blk0 + tid;
    sblk[tid] = (ib < MAXB_) ? btab[b * MAXB_ + ib] : 0;
  }
  __syncthreads();

  float4 qf[4];
  #pragma unroll
  for (int g = 0; g < 4; ++g)
    qf[g] = *(const float4*)(qkvf + (size_t)(b * 32 + h * 4 + g) * 128 + d4 * 4);

  float m[4], l[4], acc[4][4];
  #pragma unroll
  for (int g = 0; g < 4; ++g) {
    m[g] = -1e30f; l[g] = 0.f;
    #pragma unroll
    for (int j = 0; j < 4; ++j) acc[g][j] = 0.f;
  }

  for (int t = t0 + half; t < tEnd; t += 8) {
    int slot = sblk[(t >> 4) - blk0] * BS_ + (t & 15);
    const float* base = kcache + ((size_t)slot * HKV_ + h) * D_ + d4 * 4;
    const float* vbas = vcache + ((size_t)slot * HKV_ + h) * D_ + d4 * 4;
    float4 kv = *(const float4*)base;
    float4 vv = *(const float4*)vbas;

    float p0 = qf[0].x * kv.x + qf[0].y * kv.y + qf[0].z * kv.z + qf[0].w * kv.w;
    float p1 = qf[1].x * kv.x + qf[1].y * kv.y + qf[1].z * kv.z + qf[1].w * kv.w;
    float p2 = qf[2].x * kv.x + qf[2].y * kv.y + qf[2].z * kv.z + qf[2].w * kv.w;
    float p3 = qf[3].x * kv.x + qf[3].y * kv.y + qf[3].z * kv.z + qf[3].w * kv.w;
    #pragma unroll
    for (int mm = 16; mm >= 1; mm >>= 1) {
      p0 += __shfl_xor(p0, mm);
      p1 += __shfl_xor(p1, mm);
      p2 += __shfl_xor(p2, mm);
      p3 += __shfl_xor(p3, mm);
    }
    float pg[4] = {p0, p1, p2, p3};
    #pragma unroll
    for (int g = 0; g < 4; ++g) {
      float nm = fmaxf(m[g], pg[g]);
      float sc = __expf(m[g] - nm);
      float pe = __expf(pg[g] - nm);
      l[g] = l[g] * sc + pe;
      acc[g][0] = acc[g][0] * sc + pe * vv.x;
      acc[g][1] = acc[g][1] * sc + pe * vv.y;
      acc[g][2] = acc[g][2] * sc + pe * vv.z;
      acc[g][3] = acc[g][3] * sc + pe * vv.w;
      m[g] = nm;
    }
  }

  if (t1 > last && half == ((last - t0) & 7)) {
    const float* kp = qkvf + 262144 + (size_t)(b * 8 + h) * 128 + d4 * 4;
    const float* vp = qkvf + 327680 + (size_t)(b * 8 + h) * 128 + d4 * 4;
    float4 kv = *(const float4*)kp;
    float4 vv = *(const float4*)vp;
    float p0 = qf[0].x * kv.x + qf[0].y * kv.y + qf[0].z * kv.z + qf[0].w * kv.w;
    float p1 = qf[1].x * kv.x + qf[1].y * kv.y + qf[1].z * kv.z + qf[1].w * kv.w;
    float p2 = qf[2].x * kv.x + qf[2].y * kv.y + qf[2].z * kv.z + qf[2].w * kv.w;
    float p3 = qf[3].x * kv.x + qf[3].y * kv.y + qf[3].z * kv.z + qf[3].w * kv.w;
    #pragma unroll
    for (int mm = 16; mm >= 1; mm >>= 1) {
      p0 += __shfl_xor(p0, mm);
      p1 += __shfl_xor(p1, mm);
      p2 += __shfl_xor(p2, mm);
      p3 += __shfl_xor(p3, mm);
    }
    float pg[4] = {p0, p1, p2, p3};
    #pragma unroll
    for (int g = 0; g < 4; ++g) {
      float nm = fmaxf(m[g], pg[g]);
      float sc = __expf(m[g] - nm);
      float pe = __expf(pg[g] - nm);
      l[g] = l[g] * sc + pe;
      acc[g][0] = acc[g][0] * sc + pe * vv.x;
      acc[g][1] = acc[g][1] * sc + pe * vv.y;
      acc[g][2] = acc[g][2] * sc + pe * vv.z;
      acc[g][3] = acc[g][3] * sc + pe * vv.w;
      m[g] = nm;
    }
  }

  #pragma unroll
  for (int g = 0; g < 4; ++g) {
    float om = __shfl_xor(m[g], 32);
    float ol = __shfl_xor(l[g], 32);
    float M  = fmaxf(m[g], om);
    float s0 = __expf(m[g] - M);
    float s1 = __expf(om - M);
    l[g] = l[g] * s0 + ol * s1;
    #pragma unroll
    for (int j = 0; j < 4; ++j) {
      float oa = __shfl_xor(acc[g][j], 32);
      acc[g][j] = acc[g][j] * s0 + oa * s1;
    }
    m[g] = M;
  }
  if ((tid & 32) == 0) {
    int wv = tid >> 6;
    if (d4 == 0) {
      #pragma unroll
      for (int g = 0; g < 4; ++g) { wm[wv][g] = m[g]; wl[wv][g] = l[g]; }
    }
    #pragma unroll
    for (int g = 0; g < 4; ++g)
      #pragma unroll
      for (int j = 0; j < 4; ++j)
        wacc[wv][g][d4 * 4 + j] = acc[g][j];
  }
  __syncthreads();

  for (int idx = tid; idx < 512; idx += 256) {
    int g = idx >> 7, d = idx & 127;
    float M4 = fmaxf(fmaxf(wm[0][g], wm[1][g]), fmaxf(wm[2][g], wm[3][g]));
    float e0 = __expf(wm[0][g] - M4), e1 = __expf(wm[1][g] - M4);
    float e2 = __expf(wm[2][g] - M4), e3 = __expf(wm[3][g] - M4);
    float num = wacc[0][g][d] * e0 + wacc[1][g][d] * e1
              + wacc[2][g][d] * e2 + wacc[3][g][d] * e3;
    part_o[(size_t)bid * 512 + idx] = num;
    if (d == 0) {
      float lt = wl[0][g] * e0 + wl[1][g] * e1 + wl[2][g] * e2 + wl[3][g] * e3;
      part_ml[(size_t)bid * 8 + g * 2]     = M4;
      part_ml[(size_t)bid * 8 + g * 2 + 1] = lt;
    }
  }
}

// ---------------------------------------------------------------------------
// Combine split partials AND emit bf16 hi/lo XB layout for the O-GEMM.
// ---------------------------------------------------------------------------
__global__ __launch_bounds__(256) void attn_combine_xb(
    const float* __restrict__ part_o, const float* __restrict__ part_ml,
    unsigned short* __restrict__ XBhi, unsigned short* __restrict__ XBlo)
{
  const int bh = blockIdx.x;            // 0..511
  const int b = bh >> 3, h = bh & 7;
  const int tid = threadIdx.x;

  __shared__ float Sg[SPLITS][4];
  __shared__ float Dg[4];

  if (tid < 32) {
    int s = tid >> 2, g = tid & 3;
    float m = part_ml[((size_t)bh * SPLITS + s) * 8 + g * 2];
    float l = part_ml[((size_t)bh * SPLITS + s) * 8 + g * 2 + 1];
    float M = m;
    #pragma unroll
    for (int k = 4; k <= 16; k <<= 1) M = fmaxf(M, __shfl_xor(M, k));
    float scl = __expf(m - M);
    float dl = l * scl;
    #pragma unroll
    for (int k = 4; k <= 16; k <<= 1) dl += __shfl_xor(dl, k);
    Sg[s][g] = scl;
    if (s == 0) Dg[g] = dl;
  }
  __syncthreads();

  for (int idx = tid; idx < 512; idx += 256) {
    int g = idx >> 7, d = idx & 127;
    float num = 0.f;
    #pragma unroll
    for (int s = 0; s < SPLITS; ++s)
      num += Sg[s][g] * part_o[((size_t)bh * SPLITS + s) * 512 + idx];
    float val = num / Dg[g];
    int col = (h * 4 + g) * 128 + d;
    int kg = col >> 3, j = col & 7;
    unsigned short hi = f2bf(val);
    unsigned short lo = f2bf(val - bf2f(hi));
    XBhi[((size_t)kg * 64 + b) * 8 + j] = hi;
    XBlo[((size_t)kg * 64 + b) * 8 + j] = lo;
  }
}

// ---------------------------------------------------------------------------
// Sum KS partials of O-GEMM ([ks][row][batch]) -> out[b][row] via LDS
// transpose, coalesced both sides.
// ---------------------------------------------------------------------------
__global__ __launch_bounds__(256) void reduce_out_t(
    const float* __restrict__ part, float* __restrict__ out)
{
  __shared__ float t[64][65];
  const int i0 = blockIdx.x * 64;
  const int lane = threadIdx.x & 63, q = threadIdx.x >> 6;

  #pragma unroll
  for (int rr = q; rr < 64; rr += 4) {
    float s = 0.f;
    #pragma unroll 8
    for (int ks = 0; ks < KS; ++ks)
      s += part[((size_t)ks * O_ROWS + i0 + rr) * 64 + lane];
    t[rr][lane] = s;
  }
  __syncthreads();
  #pragma unroll
  for (int rr = q; rr < 64; rr += 4)
    out[(size_t)rr * O_ROWS + i0 + lane] = t[lane][rr];
}

// ---------------------------------------------------------------------------
extern "C" void kernel_launch(void* const* d_in, const int* in_sizes, int n_in,
                              void* d_out, int out_size, void* d_ws, size_t ws_size,
                              hipStream_t stream)
{
  (void)in_sizes; (void)n_in; (void)out_size; (void)ws_size;
  const float* hidden    = (const float*)d_in[0];
  const int*   positions = (const int*)d_in[1];
  const float* cosT      = (const float*)d_in[2];
  const float* sinT      = (const float*)d_in[3];
  const float* kcache    = (const float*)d_in[4];
  const float* vcache    = (const float*)d_in[5];
  const int*   btab      = (const int*)d_in[7];
  const int*   ctx       = (const int*)d_in[8];
  const float* Wq        = (const float*)d_in[9];
  const float* Wk        = (const float*)d_in[10];
  const float* Wv        = (const float*)d_in[11];
  const float* Wo        = (const float*)d_in[12];
  float* out = (float*)d_out;

  float* ws      = (float*)d_ws;
  float* region  = ws;                       // reused 3x
  float* qkvf    = region + REGION_SZ;
  unsigned short* XBhi = (unsigned short*)(qkvf + QKVF_SZ);
  unsigned short* XBlo = XBhi + XB_SZ;
  float* part1   = region;                                     // phase 1
  float* part_o  = region;                                     // phase 2
  float* part_ml = region + (size_t)B_ * HKV_ * SPLITS * 512;
  float* part3   = region;                                     // phase 3

  convert_x<<<128, 256, 0, stream>>>(hidden, XBhi, XBlo);
  gemm_mfma<<<dim3(QKV_ROWS / 128, KS), 256, 0, stream>>>(
      Wq, Wk, Wv, XBhi, XBlo, 4096, 5120, QKV_ROWS, part1);
  reduce_rope<<<768, 256, 0, stream>>>(part1, cosT, sinT, positions, qkvf);
  attn_split<<<B_ * HKV_ * SPLITS, 256, 0, stream>>>(
      qkvf, kcache, vcache, btab, ctx, part_o, part_ml);
  attn_combine_xb<<<B_ * HKV_, 256, 0, stream>>>(part_o, part_ml, XBhi, XBlo);
  gemm_mfma<<<dim3(O_ROWS / 128, KS), 256, 0, stream>>>(
      Wo, Wo, Wo, XBhi, XBlo, O_ROWS, O_ROWS, O_ROWS, part3);
  reduce_out_t<<<O_ROWS / 64, 256, 0, stream>>>(part3, out);
}